// Round 15
// baseline (356.056 us; speedup 1.0000x reference)
//
#include <hip/hip_runtime.h>
#include <hip/hip_bf16.h>

#define BATCH 2
#define NPB   2048
#define NPTS  4096   // BATCH*NPB
#define KNB   27
#define FCATC 1440
#define CSTRIDE 1696   // channel stride for slot partial sums (1440 + 256)
#define NSLOT 32
#define PBATCH 4       // points per gather block (atomic-traffic reduction)
#define INVCNT_EDGE (1.f / (float)(NPTS * KNB))

// weight-plane segment offsets (elements): layer1 2*192x96, layer2 2*384x192, layer3 2*768x384, final 256x1440
#define WOFF_L1 0
#define WOFF_L2 36864
#define WOFF_L3 184320
#define WOFF_F  774144
#define WTOTAL  1142784

typedef __hip_bfloat16 bf16;
typedef __attribute__((ext_vector_type(8))) short short8;   // 8 bf16 = 4 VGPRs (MFMA A/B frag)
typedef __attribute__((ext_vector_type(4))) float f32x4;    // MFMA C/D frag
typedef __attribute__((ext_vector_type(2))) short s16x2;    // 2 bf16 = 4B vector

__device__ __forceinline__ float b2f(bf16 v) { return __bfloat162float(v); }
__device__ __forceinline__ float su2f(short v) { return __uint_as_float(((uint)(unsigned short)v) << 16); }

// split fp32 into hi/lo bf16 pair (hi + lo ~ 16 mantissa bits)
__device__ __forceinline__ void split_bf16(float v, bf16& h, bf16& l) {
    h = __float2bfloat16(v);
    l = __float2bfloat16(v - b2f(h));
}

// load input element i from buffer p whose dtype is fp32 (f32=1) or bf16 (f32=0)
__device__ __forceinline__ float ldin(const void* p, size_t i, int f32) {
    return f32 ? ((const float*)p)[i] : b2f(((const bf16*)p)[i]);
}

// ---------------- init: zero slot accumulators + dtype-detect + convert x (fused) ----------------
__global__ void k_init(const void* __restrict__ x, int* __restrict__ flag,
                       float* __restrict__ xf, float* __restrict__ slots) {
    if (blockIdx.x < 424) {
        slots[blockIdx.x * 256 + threadIdx.x] = 0.f;
        return;
    }
    __shared__ int s;
    if (threadIdx.x == 0) s = 0;
    __syncthreads();
    const bf16* xb = (const bf16*)x;
    int local = 0;
    for (int i = threadIdx.x; i < NPTS * 3; i += 256) {
        float v = b2f(xb[i]);
        if (!(fabsf(v) < 1e4f)) local = 1;   // catches NaN/Inf/huge -> underlying fp32
    }
    if (local) s = 1;
    __syncthreads();
    int f32 = s;
    if (threadIdx.x == 0) flag[0] = f32;
    for (int i = threadIdx.x; i < NPTS * 3; i += 256) xf[i] = ldin(x, i, f32);
}

// ---------------- KNN via radix-select: top-27 by max of negative sq dist ----------------
__global__ __launch_bounds__(256) void k_knn(const float* __restrict__ x, int* __restrict__ idx) {
    __shared__ uint hist4[4][260];   // per-wave copies, padded
    __shared__ uint hist[256];
    __shared__ int  tix[NPB];
    __shared__ uint s_phigh;
    __shared__ int  s_rem, s_outcnt, s_tiecnt;

    int bn = blockIdx.x, b = bn >> 11, n = bn & (NPB - 1);
    int tid = threadIdx.x;
    int wv = tid >> 6;
    const float* xb = x + (size_t)b * NPB * 3;
    float cx = xb[n * 3 + 0], cy = xb[n * 3 + 1], cz = xb[n * 3 + 2];
    float cc = cx * cx + cy * cy + cz * cz;

    uint u[8];
    #pragma unroll
    for (int j = 0; j < 8; j++) {
        int m = j * 256 + tid;
        float mx = xb[m * 3 + 0], my = xb[m * 3 + 1], mz = xb[m * 3 + 2];
        float d = 2.f * (cx * mx + cy * my + cz * mz) - cc - (mx * mx + my * my + mz * mz);
        uint s = __float_as_uint(d);
        u[j] = (s & 0x80000000u) ? ~s : (s | 0x80000000u);
    }
    if (tid == 0) { s_phigh = 0; s_rem = KNB; s_outcnt = 0; s_tiecnt = 0; }

    for (int pass = 0; pass < 4; pass++) {
        int shift = 24 - pass * 8;
        hist[tid] = 0;
        for (int i = tid; i < 4 * 260; i += 256) ((uint*)hist4)[i] = 0;
        __syncthreads();
        uint phigh = s_phigh;
        #pragma unroll
        for (int j = 0; j < 8; j++) {
            bool in = (pass == 0) || ((u[j] >> (shift + 8)) == phigh);
            if (in) atomicAdd(&hist4[wv][(u[j] >> shift) & 0xFFu], 1u);
        }
        __syncthreads();
        hist[tid] = hist4[0][tid] + hist4[1][tid] + hist4[2][tid] + hist4[3][tid];
        __syncthreads();
        if (tid < 64) {
            int L = tid;
            uint c0 = hist[L * 4 + 0], c1 = hist[L * 4 + 1], c2 = hist[L * 4 + 2], c3 = hist[L * 4 + 3];
            uint s = c0 + c1 + c2 + c3;
            uint acc = s;
            #pragma unroll
            for (int off = 1; off < 64; off <<= 1) {
                uint t = __shfl_down(acc, off);
                if (L + off < 64) acc += t;
            }
            uint excl = acc - s;
            int rem = s_rem;
            if ((int)excl < rem && (int)acc >= rem) {
                uint cs[4] = { c0, c1, c2, c3 };
                uint cum = excl;
                int bsel = 0; uint hb = 0;
                #pragma unroll
                for (int q = 3; q >= 0; q--) {
                    if ((int)cum < rem && (int)(cum + cs[q]) >= rem && hb == 0u && bsel == 0) {
                        bsel = L * 4 + q; hb = cs[q]; cum += cs[q];
                    } else if (bsel == 0 && hb == 0u) {
                        cum += cs[q];
                    }
                }
                int strictlyAbove = (int)(cum - hb);
                s_rem = rem - strictlyAbove;
                s_phigh = (phigh << 8) | (uint)bsel;
            }
        }
        __syncthreads();
    }

    uint T = s_phigh;
    #pragma unroll
    for (int j = 0; j < 8; j++) {
        int m = j * 256 + tid;
        if (u[j] > T) {
            int p = atomicAdd(&s_outcnt, 1);
            idx[bn * KNB + p] = b * NPB + m;
        } else if (u[j] == T) {
            int p = atomicAdd(&s_tiecnt, 1);
            tix[p] = m;
        }
    }
    __syncthreads();
    int outcnt = s_outcnt, rem = s_rem, tiecnt = s_tiecnt;
    if (tiecnt == rem) {
        if (tid < rem) idx[bn * KNB + outcnt + tid] = b * NPB + tix[tid];
    } else if (tid == 0) {
        for (int t = 0; t < rem; t++) {
            int bi = 0;
            for (int q = 1; q < tiecnt; q++) if (tix[q] < tix[bi]) bi = q;
            idx[bn * KNB + outcnt + t] = b * NPB + tix[bi];
            tix[bi] = 0x7fffffff;
        }
    }
}

// ---------------- layer0 direct: u -> Ub bf16, v -> Vf f32 (Co=96) ----------------
__global__ void k_l0(const float* __restrict__ xf, const void* __restrict__ W,
                     const int* __restrict__ flag, bf16* __restrict__ Ub, float* __restrict__ Vf) {
    int i = blockIdx.x * 256 + threadIdx.x;
    if (i >= NPTS * 192) return;
    int bn = i / 192, o = i % 192;
    int f32 = flag[0];
    float x0 = xf[bn * 3 + 0], x1 = xf[bn * 3 + 1], x2 = xf[bn * 3 + 2];
    if (o < 96) {
        float r = x0 * ldin(W, o * 6 + 0, f32) + x1 * ldin(W, o * 6 + 1, f32) + x2 * ldin(W, o * 6 + 2, f32);
        Ub[(size_t)bn * 96 + o] = __float2bfloat16(r);
    } else {
        int oo = o - 96;
        float w0 = ldin(W, oo * 6 + 3, f32) - ldin(W, oo * 6 + 0, f32);
        float w1 = ldin(W, oo * 6 + 4, f32) - ldin(W, oo * 6 + 1, f32);
        float w2 = ldin(W, oo * 6 + 5, f32) - ldin(W, oo * 6 + 2, f32);
        Vf[(size_t)bn * 96 + oo] = x0 * w0 + x1 * w1 + x2 * w2;
    }
}

// ---------------- ALL weight transforms + contiguous g/b arrays in one kernel ----------------
// Weight segments as round 14 (WOFF_*). Tail (i >= WTOTAL): j<1440 -> gall[j], else ball[j-1440],
// selected from the per-layer g/b inputs by channel range {96,192,384,768}.
__global__ void k_wt_all(const void* __restrict__ W1, const void* __restrict__ W2,
                         const void* __restrict__ W3, const void* __restrict__ W4,
                         const void* __restrict__ g0, const void* __restrict__ b0,
                         const void* __restrict__ g1, const void* __restrict__ b1,
                         const void* __restrict__ g2, const void* __restrict__ b2,
                         const void* __restrict__ g3, const void* __restrict__ b3,
                         const int* __restrict__ flag,
                         bf16* __restrict__ Wh, bf16* __restrict__ Wl,
                         float* __restrict__ gall, float* __restrict__ ball) {
    int i = blockIdx.x * 256 + threadIdx.x;
    if (i >= WTOTAL + 2880) return;
    int f32 = flag[0];
    if (i >= WTOTAL) {
        int j = i - WTOTAL;
        int isb = (j >= 1440);
        int c = isb ? j - 1440 : j;
        const void* p;
        int lo;
        if (c < 96)       { p = isb ? b0 : g0; lo = 0;   }
        else if (c < 288) { p = isb ? b1 : g1; lo = 96;  }
        else if (c < 672) { p = isb ? b2 : g2; lo = 288; }
        else              { p = isb ? b3 : g3; lo = 672; }
        float v = ldin(p, c - lo, f32);
        if (isb) ball[c] = v; else gall[c] = v;
        return;
    }
    float w;
    if (i < WOFF_L2) {                     // layer1: Cin=96, Co=192, 2Cin=192
        int row = i / 96, c = i % 96;
        w = (row < 192) ? ldin(W1, (size_t)row * 192 + c, f32)
                        : ldin(W1, (size_t)(row - 192) * 192 + 96 + c, f32)
                          - ldin(W1, (size_t)(row - 192) * 192 + c, f32);
    } else if (i < WOFF_L3) {              // layer2: Cin=192, Co=384, 2Cin=384
        int j = i - WOFF_L2;
        int row = j / 192, c = j % 192;
        w = (row < 384) ? ldin(W2, (size_t)row * 384 + c, f32)
                        : ldin(W2, (size_t)(row - 384) * 384 + 192 + c, f32)
                          - ldin(W2, (size_t)(row - 384) * 384 + c, f32);
    } else if (i < WOFF_F) {               // layer3: Cin=384, Co=768, 2Cin=768
        int j = i - WOFF_L3;
        int row = j / 384, c = j % 384;
        w = (row < 768) ? ldin(W3, (size_t)row * 768 + c, f32)
                        : ldin(W3, (size_t)(row - 768) * 768 + 384 + c, f32)
                          - ldin(W3, (size_t)(row - 768) * 768 + c, f32);
    } else {                               // final: 256 x 1440 direct
        int j = i - WOFF_F;
        w = ldin(W4, j, f32);
    }
    bf16 h, l; split_bf16(w, h, l);
    Wh[i] = h; Wl[i] = l;
}

// ---------------- split-precision MFMA GEMM with fused BN+lrelu on A-load ----------------
// A = fcat pre-BN (ymax hi/lo planes + ymin bf16 plane). Per-block prologue computes
// scale/shift for its k-slice from the 32-slot stats (identical math to old k_scaleshift),
// then staging applies z = lrelu(sc*y+sh) and re-splits hi/lo (bit-identical to old apply path).
// XCD m-stripe swizzle (gridDim.y == 64). Cosplit>0: cols [0,Cosplit)->Cu bf16, rest->Cv f32;
// Cosplit==0: f32 split-K plane write (no atomics).
__global__ __launch_bounds__(256) void k_gemm_mfma(const bf16* __restrict__ Ah, const bf16* __restrict__ Al,
                                                   const bf16* __restrict__ Amn,
                                                   int lda, int aoff,
                                                   const bf16* __restrict__ Bh, const bf16* __restrict__ Bl,
                                                   int K, bf16* __restrict__ Cu, float* __restrict__ Cv,
                                                   int Cosplit, int ldc, int ksz, int zstride,
                                                   const float* __restrict__ ssum, const float* __restrict__ ssq,
                                                   const float* __restrict__ gall, const float* __restrict__ ball) {
    __shared__ bf16 Ash[64][40];   // +8 pad: 2-way max bank aliasing
    __shared__ bf16 Asl[64][40];
    __shared__ bf16 Bsh[64][40];
    __shared__ bf16 Bsl[64][40];
    __shared__ float sls[384], shs[384];
    int tid = threadIdx.x;
    int wave = tid >> 6, lane = tid & 63;
    int wm = wave >> 1, wn = wave & 1;
    int quad = lane >> 4, l15 = lane & 15;
    int Lxy = blockIdx.y * gridDim.x + blockIdx.x;
    int stripe = Lxy & 7;
    int w = Lxy >> 3;
    int mb = stripe * 8 + (w & 7);
    int nb = w >> 3;
    int m0 = mb * 64, n0 = nb * 64;
    int kbase = blockIdx.z * ksz;
    float* Cz = Cv + (size_t)blockIdx.z * zstride;
    int lr = tid >> 2, lc = (tid & 3) * 8;

    // prologue: per-channel BN scale/shift for this block's k-slice (identical to k_scaleshift math)
    for (int k = tid; k < ksz; k += 256) {
        int c = aoff + kbase + k;
        float s = 0.f, q = 0.f;
        for (int c2 = 0; c2 < NSLOT; c2++) { s += ssum[c2 * CSTRIDE + c]; q += ssq[c2 * CSTRIDE + c]; }
        float mean = s * INVCNT_EDGE;
        float var = q * INVCNT_EDGE - mean * mean;
        float sc = gall[c] * rsqrtf(var + 1e-5f);
        sls[k] = sc;
        shs[k] = ball[c] - mean * sc;
    }
    __syncthreads();

    f32x4 acc[2][2] = {};
    for (int k0 = kbase; k0 < kbase + ksz; k0 += 32) {
        size_t ao = (size_t)(m0 + lr) * lda + aoff + k0 + lc;
        size_t bo = (size_t)(n0 + lr) * K + k0 + lc;
        short8 hv = *(const short8*)&Ah[ao];
        short8 lv = *(const short8*)&Al[ao];
        short8 mv = *(const short8*)&Amn[ao];
        bf16 zh[8], zl[8];
        int kl = k0 - kbase + lc;
        #pragma unroll
        for (int j = 0; j < 8; j++) {
            float sc = sls[kl + j], sh = shs[kl + j];
            float y = (sc >= 0.f) ? (su2f(hv[j]) + su2f(lv[j])) : su2f(mv[j]);
            float z = sc * y + sh;
            z = (z >= 0.f) ? z : 0.2f * z;
            split_bf16(z, zh[j], zl[j]);
        }
        *(short8*)&Ash[lr][lc] = *(const short8*)zh;
        *(short8*)&Asl[lr][lc] = *(const short8*)zl;
        *(short8*)&Bsh[lr][lc] = *(const short8*)&Bh[bo];
        *(short8*)&Bsl[lr][lc] = *(const short8*)&Bl[bo];
        __syncthreads();
        short8 ah0 = *(const short8*)&Ash[wm * 32 + l15][quad * 8];
        short8 ah1 = *(const short8*)&Ash[wm * 32 + 16 + l15][quad * 8];
        short8 al0 = *(const short8*)&Asl[wm * 32 + l15][quad * 8];
        short8 al1 = *(const short8*)&Asl[wm * 32 + 16 + l15][quad * 8];
        short8 bh0 = *(const short8*)&Bsh[wn * 32 + l15][quad * 8];
        short8 bh1 = *(const short8*)&Bsh[wn * 32 + 16 + l15][quad * 8];
        short8 bl0 = *(const short8*)&Bsl[wn * 32 + l15][quad * 8];
        short8 bl1 = *(const short8*)&Bsl[wn * 32 + 16 + l15][quad * 8];
        acc[0][0] = __builtin_amdgcn_mfma_f32_16x16x32_bf16(ah0, bl0, acc[0][0], 0, 0, 0);
        acc[0][0] = __builtin_amdgcn_mfma_f32_16x16x32_bf16(al0, bh0, acc[0][0], 0, 0, 0);
        acc[0][0] = __builtin_amdgcn_mfma_f32_16x16x32_bf16(ah0, bh0, acc[0][0], 0, 0, 0);
        acc[0][1] = __builtin_amdgcn_mfma_f32_16x16x32_bf16(ah0, bl1, acc[0][1], 0, 0, 0);
        acc[0][1] = __builtin_amdgcn_mfma_f32_16x16x32_bf16(al0, bh1, acc[0][1], 0, 0, 0);
        acc[0][1] = __builtin_amdgcn_mfma_f32_16x16x32_bf16(ah0, bh1, acc[0][1], 0, 0, 0);
        acc[1][0] = __builtin_amdgcn_mfma_f32_16x16x32_bf16(ah1, bl0, acc[1][0], 0, 0, 0);
        acc[1][0] = __builtin_amdgcn_mfma_f32_16x16x32_bf16(al1, bh0, acc[1][0], 0, 0, 0);
        acc[1][0] = __builtin_amdgcn_mfma_f32_16x16x32_bf16(ah1, bh0, acc[1][0], 0, 0, 0);
        acc[1][1] = __builtin_amdgcn_mfma_f32_16x16x32_bf16(ah1, bl1, acc[1][1], 0, 0, 0);
        acc[1][1] = __builtin_amdgcn_mfma_f32_16x16x32_bf16(al1, bh1, acc[1][1], 0, 0, 0);
        acc[1][1] = __builtin_amdgcn_mfma_f32_16x16x32_bf16(ah1, bh1, acc[1][1], 0, 0, 0);
        __syncthreads();
    }
    #pragma unroll
    for (int mt = 0; mt < 2; mt++) {
        #pragma unroll
        for (int nt = 0; nt < 2; nt++) {
            int col = n0 + wn * 32 + nt * 16 + l15;
            #pragma unroll
            for (int i = 0; i < 4; i++) {
                int row = m0 + wm * 32 + mt * 16 + quad * 4 + i;
                if (Cosplit > 0) {
                    if (col < Cosplit) Cu[(size_t)row * Cosplit + col] = __float2bfloat16(acc[mt][nt][i]);
                    else               Cv[(size_t)row * Cosplit + col - Cosplit] = acc[mt][nt][i];
                } else {
                    Cz[(size_t)row * ldc + col] = acc[mt][nt][i];
                }
            }
        }
    }
}

// ---------------- fused gather: 2 channels/thread, XCD swizzle; stores PRE-BN ymax hi/lo + ymin bf16 ----------------
__global__ __launch_bounds__(256) void k_gather(const bf16* __restrict__ Ub, const float* __restrict__ Vf,
                                                const int* __restrict__ idx,
                                                bf16* __restrict__ fch, bf16* __restrict__ fcl,
                                                bf16* __restrict__ fmn,
                                                float* __restrict__ ssum, float* __restrict__ ssq,
                                                int Co, int out_off) {
    __shared__ int srow[PBATCH * KNB];
    int tid = threadIdx.x;
    int L = blockIdx.y * gridDim.x + blockIdx.x;
    int batch = L & 1;
    int w = L >> 1;
    int pg = batch * 512 + (w & 511);       // point group within [0,1024)
    int chunk = w >> 9;                     // channel-pair chunk
    int p0 = pg * PBATCH;
    if (tid < PBATCH * KNB) srow[tid] = idx[p0 * KNB + tid] * Co;
    __syncthreads();
    int P = Co >> 1;
    int op = chunk * 256 + tid;
    if (op >= P) return;
    int o = op * 2;
    int slot = pg & (NSLOT - 1);
    float s0 = 0.f, s1 = 0.f, q0 = 0.f, q1 = 0.f;
    #pragma unroll 1
    for (int p = 0; p < PBATCH; p++) {
        int bn = p0 + p;
        float2 vv = *(const float2*)&Vf[(size_t)bn * Co + o];
        float ymax0 = -INFINITY, ymax1 = -INFINITY, ymin0 = INFINITY, ymin1 = INFINITY;
        #pragma unroll
        for (int k = 0; k < KNB; k++) {
            uint wb = *(const uint*)&Ub[(size_t)srow[p * KNB + k] + o];
            float y0 = __uint_as_float(wb << 16) + vv.x;
            float y1 = __uint_as_float(wb & 0xffff0000u) + vv.y;
            ymax0 = fmaxf(ymax0, y0); ymin0 = fminf(ymin0, y0); s0 += y0; q0 += y0 * y0;
            ymax1 = fmaxf(ymax1, y1); ymin1 = fminf(ymin1, y1); s1 += y1; q1 += y1 * y1;
        }
        size_t fi = (size_t)bn * FCATC + out_off + o;
        bf16 hh[2], ll[2], mm[2];
        split_bf16(ymax0, hh[0], ll[0]);
        split_bf16(ymax1, hh[1], ll[1]);
        mm[0] = __float2bfloat16(ymin0);
        mm[1] = __float2bfloat16(ymin1);
        *(s16x2*)&fch[fi] = *(const s16x2*)hh;
        *(s16x2*)&fcl[fi] = *(const s16x2*)ll;
        *(s16x2*)&fmn[fi] = *(const s16x2*)mm;
    }
    atomicAdd(&ssum[slot * CSTRIDE + o + 0], s0);
    atomicAdd(&ssum[slot * CSTRIDE + o + 1], s1);
    atomicAdd(&ssq [slot * CSTRIDE + o + 0], q0);
    atomicAdd(&ssq [slot * CSTRIDE + o + 1], q1);
}

// ---------------- final: reduce 5 split-K planes -> Y4 + BN stats (no atomics) ----------------
__global__ void k_stats_final(const float* __restrict__ part, float* __restrict__ Y,
                              float* __restrict__ ssum, float* __restrict__ ssq) {
    int o = threadIdx.x;
    int p0 = blockIdx.x * 128;
    const size_t PL = (size_t)NPTS * 256;
    float s = 0, q = 0;
    for (int p = 0; p < 128; p++) {
        size_t i = (size_t)(p0 + p) * 256 + o;
        float y = part[i] + part[i + PL] + part[i + 2 * PL] + part[i + 3 * PL] + part[i + 4 * PL];
        Y[i] = y;
        s += y; q += y * y;
    }
    ssum[blockIdx.x * CSTRIDE + o] = s;
    ssq [blockIdx.x * CSTRIDE + o] = q;
}

// ---------------- feats: fused final scale/shift + BN + lrelu + per-chunk max ----------------
__global__ void k_feats(const float* __restrict__ Y, const float* __restrict__ ssum,
                        const float* __restrict__ ssq, const void* __restrict__ g,
                        const void* __restrict__ bb, const int* __restrict__ flag,
                        void* __restrict__ out, float* __restrict__ partial) {
    int o = threadIdx.x;
    int chunk = blockIdx.x;
    int bn0 = chunk * 64;
    int f32 = flag[0];
    float s = 0.f, q = 0.f;
    for (int c = 0; c < NSLOT; c++) { s += ssum[c * CSTRIDE + o]; q += ssq[c * CSTRIDE + o]; }
    float mean = s * (1.f / (float)NPTS);
    float var = q * (1.f / (float)NPTS) - mean * mean;
    float sc = ldin(g, o, f32) * rsqrtf(var + 1e-5f);
    float sh = ldin(bb, o, f32) - mean * sc;
    float best = -INFINITY;
    for (int i = 0; i < 64; i++) {
        int bn = bn0 + i;
        float z = sc * Y[(size_t)bn * 256 + o] + sh;
        z = (z >= 0.f) ? z : 0.2f * z;
        size_t oi = (size_t)BATCH * 256 + (size_t)bn * 256 + o;
        if (f32) ((float*)out)[oi] = z;
        else     ((bf16*)out)[oi] = __float2bfloat16(z);
        best = fmaxf(best, z);
    }
    partial[chunk * 256 + o] = best;
}

__global__ void k_gmax(const float* __restrict__ partial, void* __restrict__ out, const int* __restrict__ flag) {
    int o = threadIdx.x;
    int b = blockIdx.x;
    float best = -INFINITY;
    for (int c = 0; c < 32; c++) best = fmaxf(best, partial[(b * 32 + c) * 256 + o]);
    if (flag[0]) ((float*)out)[b * 256 + o] = best;
    else         ((bf16*)out)[b * 256 + o] = __float2bfloat16(best);
}

// ---------------- launch ----------------
extern "C" void kernel_launch(void* const* d_in, const int* in_sizes, int n_in,
                              void* d_out, int out_size, void* d_ws, size_t ws_size,
                              hipStream_t stream) {
    const void* x = d_in[0];

    char* ws = (char*)d_ws;
    int*   idx    = (int*)  (ws + 0);                 // 4096*27 int
    bf16*  Ub     = (bf16*) (ws + 442368);            // 4096 x 768 bf16 (u, 6.29 MB)
    float* Vf     = (float*)(ws + 6733824);           // 4096 x 768 f32 (v, 12.58 MB)
    float* part   = (float*)(ws + 442368);            // reused after layers: 5 x 4096 x 256 f32 (21 MB)
    bf16*  fch    = (bf16*) (ws + 25608192);          // 4096 x 1440 bf16 (pre-BN ymax hi)
    bf16*  fcl    = (bf16*) (ws + 37404672);          // 4096 x 1440 bf16 (pre-BN ymax lo)
    float* Y4     = (float*)(ws + 49201152);          // 4096 x 256 f32
    bf16*  Whall  = (bf16*) (ws + 53395456);          // WTOTAL bf16 (hi planes, 2.29 MB)
    bf16*  Wlall  = (bf16*) (ws + 55681024);          // WTOTAL bf16 (lo planes)
    float* slots  = (float*)(ws + 57966592);          // 2 x 32 x 1696 f32 (434176 B)
    float* ssum   = slots;
    float* ssq    = slots + NSLOT * CSTRIDE;
    float* partial= (float*)(ws + 58414336);          // 64 x 256
    float* xf     = (float*)(ws + 58479872);          // 12288 f32
    int*   flag   = (int*)  (ws + 58529024);          // 1
    bf16*  fmn    = (bf16*) (ws + 58531840);          // 4096 x 1440 bf16 (ymin, 11.80 MB)
    float* gall   = (float*)(ws + 70328320);          // 1440 f32
    float* ball   = (float*)(ws + 70334080);          // 1440 f32

    const int Cin[4]  = {3, 96, 192, 384};
    const int Co[4]   = {96, 192, 384, 768};
    const int ooff[4] = {0, 96, 288, 672};
    const int soff[5] = {0, 96, 288, 672, 1440};
    const int woff[4] = {0, WOFF_L1, WOFF_L2, WOFF_L3};   // weight plane offsets (layers 1..3 used)

    hipLaunchKernelGGL(k_init, dim3(425), dim3(256), 0, stream, x, flag, xf, slots);
    hipLaunchKernelGGL(k_knn, dim3(NPTS), dim3(256), 0, stream, xf, idx);
    hipLaunchKernelGGL(k_wt_all, dim3((WTOTAL + 2880 + 255) / 256), dim3(256), 0, stream,
                       d_in[4], d_in[7], d_in[10], d_in[13],
                       d_in[2], d_in[3], d_in[5], d_in[6],
                       d_in[8], d_in[9], d_in[11], d_in[12],
                       flag, Whall, Wlall, gall, ball);

    for (int L = 0; L < 4; L++) {
        int N2 = 2 * Co[L];
        if (L == 0) {
            hipLaunchKernelGGL(k_l0, dim3((NPTS * 192 + 255) / 256), dim3(256), 0, stream,
                               xf, d_in[1], flag, Ub, Vf);
        } else {
            hipLaunchKernelGGL(k_gemm_mfma, dim3(N2 / 64, NPTS / 64, 1), dim3(256), 0, stream,
                               fch, fcl, fmn, FCATC, ooff[L - 1],
                               Whall + woff[L], Wlall + woff[L], Cin[L],
                               Ub, Vf, Co[L], 0, Cin[L], 0,
                               ssum, ssq, gall, ball);
        }
        int nchunks = ((Co[L] / 2) + 255) / 256;
        hipLaunchKernelGGL(k_gather, dim3(NPTS / PBATCH, nchunks), dim3(256), 0, stream,
                           Ub, Vf, idx, fch, fcl, fmn, ssum + soff[L], ssq + soff[L], Co[L], ooff[L]);
    }

    // final 1440 -> 256: split-K x5 into disjoint planes (reusing Ub/Vf region), then fused reduce+stats
    hipLaunchKernelGGL(k_gemm_mfma, dim3(256 / 64, NPTS / 64, 5), dim3(256), 0, stream,
                       fch, fcl, fmn, FCATC, 0,
                       Whall + WOFF_F, Wlall + WOFF_F, FCATC,
                       (bf16*)nullptr, part, 0, 256, 288, NPTS * 256,
                       ssum, ssq, gall, ball);
    hipLaunchKernelGGL(k_stats_final, dim3(32), dim3(256), 0, stream, part, Y4, ssum + soff[4], ssq + soff[4]);
    hipLaunchKernelGGL(k_feats, dim3(64), dim3(256), 0, stream, Y4, ssum + soff[4], ssq + soff[4],
                       d_in[14], d_in[15], flag, d_out, partial);
    hipLaunchKernelGGL(k_gmax, dim3(BATCH), dim3(256), 0, stream, partial, d_out, flag);
}

// Round 16
// 352.491 us; speedup vs baseline: 1.0101x; 1.0101x over previous
//
#include <hip/hip_runtime.h>
#include <hip/hip_bf16.h>

#define BATCH 2
#define NPB   2048
#define NPTS  4096   // BATCH*NPB
#define KNB   27
#define FCATC 1440
#define CSTRIDE 1696   // channel stride for slot partial sums (1440 + 256)
#define NSLOT 32
#define PBATCH 4       // points per gather block (atomic-traffic reduction)

// weight-plane segment offsets (elements): layer1 2*192x96, layer2 2*384x192, layer3 2*768x384, final 256x1440
#define WOFF_L1 0
#define WOFF_L2 36864
#define WOFF_L3 184320
#define WOFF_F  774144
#define WTOTAL  1142784

typedef __hip_bfloat16 bf16;
typedef __attribute__((ext_vector_type(8))) short short8;   // 8 bf16 = 4 VGPRs (MFMA A/B frag)
typedef __attribute__((ext_vector_type(4))) float f32x4;    // MFMA C/D frag
typedef __attribute__((ext_vector_type(2))) short s16x2;    // 2 bf16 = 4B vector

__device__ __forceinline__ float b2f(bf16 v) { return __bfloat162float(v); }

// split fp32 into hi/lo bf16 pair (hi + lo ~ 16 mantissa bits)
__device__ __forceinline__ void split_bf16(float v, bf16& h, bf16& l) {
    h = __float2bfloat16(v);
    l = __float2bfloat16(v - b2f(h));
}

// load input element i from buffer p whose dtype is fp32 (f32=1) or bf16 (f32=0)
__device__ __forceinline__ float ldin(const void* p, size_t i, int f32) {
    return f32 ? ((const float*)p)[i] : b2f(((const bf16*)p)[i]);
}

// ---------------- init: zero slot accumulators + dtype-detect + convert x (fused) ----------------
__global__ void k_init(const void* __restrict__ x, int* __restrict__ flag,
                       float* __restrict__ xf, float* __restrict__ slots) {
    if (blockIdx.x < 424) {
        slots[blockIdx.x * 256 + threadIdx.x] = 0.f;
        return;
    }
    __shared__ int s;
    if (threadIdx.x == 0) s = 0;
    __syncthreads();
    const bf16* xb = (const bf16*)x;
    int local = 0;
    for (int i = threadIdx.x; i < NPTS * 3; i += 256) {
        float v = b2f(xb[i]);
        if (!(fabsf(v) < 1e4f)) local = 1;   // catches NaN/Inf/huge -> underlying fp32
    }
    if (local) s = 1;
    __syncthreads();
    int f32 = s;
    if (threadIdx.x == 0) flag[0] = f32;
    for (int i = threadIdx.x; i < NPTS * 3; i += 256) xf[i] = ldin(x, i, f32);
}

// ---------------- KNN via radix-select: top-27 by max of negative sq dist ----------------
__global__ __launch_bounds__(256) void k_knn(const float* __restrict__ x, int* __restrict__ idx) {
    __shared__ uint hist4[4][260];   // per-wave copies, padded
    __shared__ uint hist[256];
    __shared__ int  tix[NPB];
    __shared__ uint s_phigh;
    __shared__ int  s_rem, s_outcnt, s_tiecnt;

    int bn = blockIdx.x, b = bn >> 11, n = bn & (NPB - 1);
    int tid = threadIdx.x;
    int wv = tid >> 6;
    const float* xb = x + (size_t)b * NPB * 3;
    float cx = xb[n * 3 + 0], cy = xb[n * 3 + 1], cz = xb[n * 3 + 2];
    float cc = cx * cx + cy * cy + cz * cz;

    uint u[8];
    #pragma unroll
    for (int j = 0; j < 8; j++) {
        int m = j * 256 + tid;
        float mx = xb[m * 3 + 0], my = xb[m * 3 + 1], mz = xb[m * 3 + 2];
        float d = 2.f * (cx * mx + cy * my + cz * mz) - cc - (mx * mx + my * my + mz * mz);
        uint s = __float_as_uint(d);
        u[j] = (s & 0x80000000u) ? ~s : (s | 0x80000000u);
    }
    if (tid == 0) { s_phigh = 0; s_rem = KNB; s_outcnt = 0; s_tiecnt = 0; }

    for (int pass = 0; pass < 4; pass++) {
        int shift = 24 - pass * 8;
        hist[tid] = 0;
        for (int i = tid; i < 4 * 260; i += 256) ((uint*)hist4)[i] = 0;
        __syncthreads();
        uint phigh = s_phigh;
        #pragma unroll
        for (int j = 0; j < 8; j++) {
            bool in = (pass == 0) || ((u[j] >> (shift + 8)) == phigh);
            if (in) atomicAdd(&hist4[wv][(u[j] >> shift) & 0xFFu], 1u);
        }
        __syncthreads();
        hist[tid] = hist4[0][tid] + hist4[1][tid] + hist4[2][tid] + hist4[3][tid];
        __syncthreads();
        if (tid < 64) {
            int L = tid;
            uint c0 = hist[L * 4 + 0], c1 = hist[L * 4 + 1], c2 = hist[L * 4 + 2], c3 = hist[L * 4 + 3];
            uint s = c0 + c1 + c2 + c3;
            uint acc = s;
            #pragma unroll
            for (int off = 1; off < 64; off <<= 1) {
                uint t = __shfl_down(acc, off);
                if (L + off < 64) acc += t;
            }
            uint excl = acc - s;
            int rem = s_rem;
            if ((int)excl < rem && (int)acc >= rem) {
                uint cs[4] = { c0, c1, c2, c3 };
                uint cum = excl;
                int bsel = 0; uint hb = 0;
                #pragma unroll
                for (int q = 3; q >= 0; q--) {
                    if ((int)cum < rem && (int)(cum + cs[q]) >= rem && hb == 0u && bsel == 0) {
                        bsel = L * 4 + q; hb = cs[q]; cum += cs[q];
                    } else if (bsel == 0 && hb == 0u) {
                        cum += cs[q];
                    }
                }
                int strictlyAbove = (int)(cum - hb);
                s_rem = rem - strictlyAbove;
                s_phigh = (phigh << 8) | (uint)bsel;
            }
        }
        __syncthreads();
    }

    uint T = s_phigh;
    #pragma unroll
    for (int j = 0; j < 8; j++) {
        int m = j * 256 + tid;
        if (u[j] > T) {
            int p = atomicAdd(&s_outcnt, 1);
            idx[bn * KNB + p] = b * NPB + m;
        } else if (u[j] == T) {
            int p = atomicAdd(&s_tiecnt, 1);
            tix[p] = m;
        }
    }
    __syncthreads();
    int outcnt = s_outcnt, rem = s_rem, tiecnt = s_tiecnt;
    if (tiecnt == rem) {
        if (tid < rem) idx[bn * KNB + outcnt + tid] = b * NPB + tix[tid];
    } else if (tid == 0) {
        for (int t = 0; t < rem; t++) {
            int bi = 0;
            for (int q = 1; q < tiecnt; q++) if (tix[q] < tix[bi]) bi = q;
            idx[bn * KNB + outcnt + t] = b * NPB + tix[bi];
            tix[bi] = 0x7fffffff;
        }
    }
}

// ---------------- layer0 direct: u -> Ub bf16, v -> Vf f32 (Co=96) ----------------
__global__ void k_l0(const float* __restrict__ xf, const void* __restrict__ W,
                     const int* __restrict__ flag, bf16* __restrict__ Ub, float* __restrict__ Vf) {
    int i = blockIdx.x * 256 + threadIdx.x;
    if (i >= NPTS * 192) return;
    int bn = i / 192, o = i % 192;
    int f32 = flag[0];
    float x0 = xf[bn * 3 + 0], x1 = xf[bn * 3 + 1], x2 = xf[bn * 3 + 2];
    if (o < 96) {
        float r = x0 * ldin(W, o * 6 + 0, f32) + x1 * ldin(W, o * 6 + 1, f32) + x2 * ldin(W, o * 6 + 2, f32);
        Ub[(size_t)bn * 96 + o] = __float2bfloat16(r);
    } else {
        int oo = o - 96;
        float w0 = ldin(W, oo * 6 + 3, f32) - ldin(W, oo * 6 + 0, f32);
        float w1 = ldin(W, oo * 6 + 4, f32) - ldin(W, oo * 6 + 1, f32);
        float w2 = ldin(W, oo * 6 + 5, f32) - ldin(W, oo * 6 + 2, f32);
        Vf[(size_t)bn * 96 + oo] = x0 * w0 + x1 * w1 + x2 * w2;
    }
}

// ---------------- ALL weight transforms in one kernel -> contiguous hi/lo planes ----------------
__global__ void k_wt_all(const void* __restrict__ W1, const void* __restrict__ W2,
                         const void* __restrict__ W3, const void* __restrict__ W4,
                         const int* __restrict__ flag,
                         bf16* __restrict__ Wh, bf16* __restrict__ Wl) {
    int i = blockIdx.x * 256 + threadIdx.x;
    if (i >= WTOTAL) return;
    int f32 = flag[0];
    float w;
    if (i < WOFF_L2) {                     // layer1: Cin=96, Co=192, 2Cin=192
        int row = i / 96, c = i % 96;
        w = (row < 192) ? ldin(W1, (size_t)row * 192 + c, f32)
                        : ldin(W1, (size_t)(row - 192) * 192 + 96 + c, f32)
                          - ldin(W1, (size_t)(row - 192) * 192 + c, f32);
    } else if (i < WOFF_L3) {              // layer2: Cin=192, Co=384, 2Cin=384
        int j = i - WOFF_L2;
        int row = j / 192, c = j % 192;
        w = (row < 384) ? ldin(W2, (size_t)row * 384 + c, f32)
                        : ldin(W2, (size_t)(row - 384) * 384 + 192 + c, f32)
                          - ldin(W2, (size_t)(row - 384) * 384 + c, f32);
    } else if (i < WOFF_F) {               // layer3: Cin=384, Co=768, 2Cin=768
        int j = i - WOFF_L3;
        int row = j / 384, c = j % 384;
        w = (row < 768) ? ldin(W3, (size_t)row * 768 + c, f32)
                        : ldin(W3, (size_t)(row - 768) * 768 + 384 + c, f32)
                          - ldin(W3, (size_t)(row - 768) * 768 + c, f32);
    } else {                               // final: 256 x 1440 direct
        int j = i - WOFF_F;
        w = ldin(W4, j, f32);
    }
    bf16 h, l; split_bf16(w, h, l);
    Wh[i] = h; Wl[i] = l;
}

// ---------------- split-precision MFMA GEMM: C = (Ah+Al) * (Bh+Bl)^T, ~fp32 accuracy ----------------
// 128x128 block (4 waves, each 64x64 = 4x4 sub-tiles of 16x16): 16 frag reads feed 48 MFMA per wave
// per k-32 tile -> 2x better LDS:MFMA ratio vs 64x64 block (which measured MfmaUtil 10%).
// XCD swizzle for gridDim.y==32: mb = (Lxy&7)*4 + (w&3), nb = w>>2 (bijective).
// Cosplit>0: cols [0,Cosplit)->Cu bf16, rest->Cv f32; Cosplit==0: f32 split-K plane write.
__global__ __launch_bounds__(256) void k_gemm_mfma(const bf16* __restrict__ Ah, const bf16* __restrict__ Al,
                                                   int lda, int aoff,
                                                   const bf16* __restrict__ Bh, const bf16* __restrict__ Bl,
                                                   int K, bf16* __restrict__ Cu, float* __restrict__ Cv,
                                                   int Cosplit, int ldc, int ksz, int zstride) {
    __shared__ bf16 Ash[128][40];   // +8 pad: 2-way max bank aliasing
    __shared__ bf16 Asl[128][40];
    __shared__ bf16 Bsh[128][40];
    __shared__ bf16 Bsl[128][40];
    int tid = threadIdx.x;
    int wave = tid >> 6, lane = tid & 63;
    int wm = wave >> 1, wn = wave & 1;
    int quad = lane >> 4, l15 = lane & 15;
    int Lxy = blockIdx.y * gridDim.x + blockIdx.x;
    int stripe = Lxy & 7;
    int w = Lxy >> 3;
    int mb = stripe * 4 + (w & 3);
    int nb = w >> 2;
    int m0 = mb * 128, n0 = nb * 128;
    int kbase = blockIdx.z * ksz;
    float* Cz = Cv + (size_t)blockIdx.z * zstride;
    int lr = tid >> 2, lc = (tid & 3) * 8;

    f32x4 acc[4][4] = {};
    for (int k0 = kbase; k0 < kbase + ksz; k0 += 32) {
        size_t ao0 = (size_t)(m0 + lr) * lda + aoff + k0 + lc;
        size_t ao1 = (size_t)(m0 + 64 + lr) * lda + aoff + k0 + lc;
        size_t bo0 = (size_t)(n0 + lr) * K + k0 + lc;
        size_t bo1 = (size_t)(n0 + 64 + lr) * K + k0 + lc;
        *(short8*)&Ash[lr][lc]      = *(const short8*)&Ah[ao0];
        *(short8*)&Ash[lr + 64][lc] = *(const short8*)&Ah[ao1];
        *(short8*)&Asl[lr][lc]      = *(const short8*)&Al[ao0];
        *(short8*)&Asl[lr + 64][lc] = *(const short8*)&Al[ao1];
        *(short8*)&Bsh[lr][lc]      = *(const short8*)&Bh[bo0];
        *(short8*)&Bsh[lr + 64][lc] = *(const short8*)&Bh[bo1];
        *(short8*)&Bsl[lr][lc]      = *(const short8*)&Bl[bo0];
        *(short8*)&Bsl[lr + 64][lc] = *(const short8*)&Bl[bo1];
        __syncthreads();
        short8 ah[4], al[4], bh[4], bl[4];
        #pragma unroll
        for (int mt = 0; mt < 4; mt++) {
            ah[mt] = *(const short8*)&Ash[wm * 64 + mt * 16 + l15][quad * 8];
            al[mt] = *(const short8*)&Asl[wm * 64 + mt * 16 + l15][quad * 8];
        }
        #pragma unroll
        for (int nt = 0; nt < 4; nt++) {
            bh[nt] = *(const short8*)&Bsh[wn * 64 + nt * 16 + l15][quad * 8];
            bl[nt] = *(const short8*)&Bsl[wn * 64 + nt * 16 + l15][quad * 8];
        }
        #pragma unroll
        for (int mt = 0; mt < 4; mt++) {
            #pragma unroll
            for (int nt = 0; nt < 4; nt++) {
                acc[mt][nt] = __builtin_amdgcn_mfma_f32_16x16x32_bf16(ah[mt], bl[nt], acc[mt][nt], 0, 0, 0);
                acc[mt][nt] = __builtin_amdgcn_mfma_f32_16x16x32_bf16(al[mt], bh[nt], acc[mt][nt], 0, 0, 0);
                acc[mt][nt] = __builtin_amdgcn_mfma_f32_16x16x32_bf16(ah[mt], bh[nt], acc[mt][nt], 0, 0, 0);
            }
        }
        __syncthreads();
    }
    #pragma unroll
    for (int mt = 0; mt < 4; mt++) {
        #pragma unroll
        for (int nt = 0; nt < 4; nt++) {
            int col = n0 + wn * 64 + nt * 16 + l15;
            #pragma unroll
            for (int i = 0; i < 4; i++) {
                int row = m0 + wm * 64 + mt * 16 + quad * 4 + i;
                if (Cosplit > 0) {
                    if (col < Cosplit) Cu[(size_t)row * Cosplit + col] = __float2bfloat16(acc[mt][nt][i]);
                    else               Cv[(size_t)row * Cosplit + col - Cosplit] = acc[mt][nt][i];
                } else {
                    Cz[(size_t)row * ldc + col] = acc[mt][nt][i];
                }
            }
        }
    }
}

// ---------------- fused gather: 2 channels/thread (uint = 2x bf16), XCD-aware swizzle ----------------
__global__ __launch_bounds__(256) void k_gather(const bf16* __restrict__ Ub, float* __restrict__ Vf,
                                                const int* __restrict__ idx,
                                                bf16* __restrict__ fch, bf16* __restrict__ fcl,
                                                float* __restrict__ ssum, float* __restrict__ ssq,
                                                int Co, int out_off) {
    __shared__ int srow[PBATCH * KNB];
    int tid = threadIdx.x;
    int L = blockIdx.y * gridDim.x + blockIdx.x;
    int batch = L & 1;
    int w = L >> 1;
    int pg = batch * 512 + (w & 511);       // point group within [0,1024)
    int chunk = w >> 9;                     // channel-pair chunk
    int p0 = pg * PBATCH;
    if (tid < PBATCH * KNB) srow[tid] = idx[p0 * KNB + tid] * Co;
    __syncthreads();
    int P = Co >> 1;
    int op = chunk * 256 + tid;
    if (op >= P) return;
    int o = op * 2;
    int slot = pg & (NSLOT - 1);
    float s0 = 0.f, s1 = 0.f, q0 = 0.f, q1 = 0.f;
    #pragma unroll 1
    for (int p = 0; p < PBATCH; p++) {
        int bn = p0 + p;
        float2 vv = *(const float2*)&Vf[(size_t)bn * Co + o];
        float ymax0 = -INFINITY, ymax1 = -INFINITY, ymin0 = INFINITY, ymin1 = INFINITY;
        #pragma unroll
        for (int k = 0; k < KNB; k++) {
            uint wb = *(const uint*)&Ub[(size_t)srow[p * KNB + k] + o];
            float y0 = __uint_as_float(wb << 16) + vv.x;
            float y1 = __uint_as_float(wb & 0xffff0000u) + vv.y;
            ymax0 = fmaxf(ymax0, y0); ymin0 = fminf(ymin0, y0); s0 += y0; q0 += y0 * y0;
            ymax1 = fmaxf(ymax1, y1); ymin1 = fminf(ymin1, y1); s1 += y1; q1 += y1 * y1;
        }
        size_t fi = (size_t)bn * FCATC + out_off + o;
        bf16 hh[2], ll[2];
        split_bf16(ymax0, hh[0], ll[0]);
        split_bf16(ymax1, hh[1], ll[1]);
        *(s16x2*)&fch[fi] = *(const s16x2*)hh;
        *(s16x2*)&fcl[fi] = *(const s16x2*)ll;
        *(float2*)&Vf[(size_t)bn * Co + o] = make_float2(ymin0, ymin1);   // stash ymin
    }
    atomicAdd(&ssum[slot * CSTRIDE + o + 0], s0);
    atomicAdd(&ssum[slot * CSTRIDE + o + 1], s1);
    atomicAdd(&ssq [slot * CSTRIDE + o + 0], q0);
    atomicAdd(&ssq [slot * CSTRIDE + o + 1], q1);
}

// ---------------- scale/shift from 32-slot partials (edge layers) ----------------
__global__ void k_scaleshift(const float* __restrict__ ssum, const float* __restrict__ ssq,
                             const void* __restrict__ g, const void* __restrict__ bb,
                             const int* __restrict__ flag,
                             float* __restrict__ scale, float* __restrict__ shift, int Co, float invcnt) {
    int o = blockIdx.x * 256 + threadIdx.x;
    if (o >= Co) return;
    int f32 = flag[0];
    float s = 0.f, q = 0.f;
    for (int c = 0; c < NSLOT; c++) { s += ssum[c * CSTRIDE + o]; q += ssq[c * CSTRIDE + o]; }
    float mean = s * invcnt;
    float var = q * invcnt - mean * mean;
    float sc = ldin(g, o, f32) * rsqrtf(var + 1e-5f);
    scale[o] = sc;
    shift[o] = ldin(bb, o, f32) - mean * sc;
}

// ---------------- apply BN + lrelu to the pooled value (in place in fcat hi/lo) ----------------
__global__ __launch_bounds__(256) void k_apply(const float* __restrict__ Vf,
                                               const float* __restrict__ scale, const float* __restrict__ shift,
                                               bf16* __restrict__ fch, bf16* __restrict__ fcl,
                                               int Co, int out_off) {
    int bn = blockIdx.x;
    for (int o = threadIdx.x; o < Co; o += 256) {
        float sc = scale[o], sh = shift[o];
        size_t fi = (size_t)bn * FCATC + out_off + o;
        float y = (sc >= 0.f) ? (b2f(fch[fi]) + b2f(fcl[fi]))
                              : Vf[(size_t)bn * Co + o];           // ymin if negative scale
        float z = sc * y + sh;
        z = (z >= 0.f) ? z : 0.2f * z;
        bf16 h, l; split_bf16(z, h, l);
        fch[fi] = h; fcl[fi] = l;
    }
}

// ---------------- final: reduce 5 split-K planes -> Y4 + BN stats (no atomics) ----------------
__global__ void k_stats_final(const float* __restrict__ part, float* __restrict__ Y,
                              float* __restrict__ ssum, float* __restrict__ ssq) {
    int o = threadIdx.x;
    int p0 = blockIdx.x * 128;
    const size_t PL = (size_t)NPTS * 256;
    float s = 0, q = 0;
    for (int p = 0; p < 128; p++) {
        size_t i = (size_t)(p0 + p) * 256 + o;
        float y = part[i] + part[i + PL] + part[i + 2 * PL] + part[i + 3 * PL] + part[i + 4 * PL];
        Y[i] = y;
        s += y; q += y * y;
    }
    ssum[blockIdx.x * CSTRIDE + o] = s;
    ssq [blockIdx.x * CSTRIDE + o] = q;
}

// ---------------- feats: fused final scale/shift + BN + lrelu + per-chunk max ----------------
__global__ void k_feats(const float* __restrict__ Y, const float* __restrict__ ssum,
                        const float* __restrict__ ssq, const void* __restrict__ g,
                        const void* __restrict__ bb, const int* __restrict__ flag,
                        void* __restrict__ out, float* __restrict__ partial) {
    int o = threadIdx.x;
    int chunk = blockIdx.x;
    int bn0 = chunk * 64;
    int f32 = flag[0];
    float s = 0.f, q = 0.f;
    for (int c = 0; c < NSLOT; c++) { s += ssum[c * CSTRIDE + o]; q += ssq[c * CSTRIDE + o]; }
    float mean = s * (1.f / (float)NPTS);
    float var = q * (1.f / (float)NPTS) - mean * mean;
    float sc = ldin(g, o, f32) * rsqrtf(var + 1e-5f);
    float sh = ldin(bb, o, f32) - mean * sc;
    float best = -INFINITY;
    for (int i = 0; i < 64; i++) {
        int bn = bn0 + i;
        float z = sc * Y[(size_t)bn * 256 + o] + sh;
        z = (z >= 0.f) ? z : 0.2f * z;
        size_t oi = (size_t)BATCH * 256 + (size_t)bn * 256 + o;
        if (f32) ((float*)out)[oi] = z;
        else     ((bf16*)out)[oi] = __float2bfloat16(z);
        best = fmaxf(best, z);
    }
    partial[chunk * 256 + o] = best;
}

__global__ void k_gmax(const float* __restrict__ partial, void* __restrict__ out, const int* __restrict__ flag) {
    int o = threadIdx.x;
    int b = blockIdx.x;
    float best = -INFINITY;
    for (int c = 0; c < 32; c++) best = fmaxf(best, partial[(b * 32 + c) * 256 + o]);
    if (flag[0]) ((float*)out)[b * 256 + o] = best;
    else         ((bf16*)out)[b * 256 + o] = __float2bfloat16(best);
}

// ---------------- launch ----------------
extern "C" void kernel_launch(void* const* d_in, const int* in_sizes, int n_in,
                              void* d_out, int out_size, void* d_ws, size_t ws_size,
                              hipStream_t stream) {
    const void* x = d_in[0];

    char* ws = (char*)d_ws;
    int*   idx    = (int*)  (ws + 0);                 // 4096*27 int
    bf16*  Ub     = (bf16*) (ws + 442368);            // 4096 x 768 bf16 (u, 6.29 MB)
    float* Vf     = (float*)(ws + 6733824);           // 4096 x 768 f32 (v/ymin, 12.58 MB)
    float* part   = (float*)(ws + 442368);            // reused after layers: 5 x 4096 x 256 f32 (21 MB)
    bf16*  fch    = (bf16*) (ws + 25608192);          // 4096 x 1440 bf16 (hi)
    bf16*  fcl    = (bf16*) (ws + 37404672);          // 4096 x 1440 bf16 (lo)
    float* Y4     = (float*)(ws + 49201152);          // 4096 x 256 f32
    bf16*  Whall  = (bf16*) (ws + 53395456);          // WTOTAL bf16 (hi planes, 2.29 MB)
    bf16*  Wlall  = (bf16*) (ws + 55681024);          // WTOTAL bf16 (lo planes)
    float* slots  = (float*)(ws + 57966592);          // 2 x 32 x 1696 f32 (434176 B)
    float* ssum   = slots;
    float* ssq    = slots + NSLOT * CSTRIDE;
    float* scales = (float*)(ws + 58400768);          // 1696
    float* shifts = (float*)(ws + 58407552);          // 1696
    float* partial= (float*)(ws + 58414336);          // 64 x 256
    float* xf     = (float*)(ws + 58479872);          // 12288 f32
    int*   flag   = (int*)  (ws + 58529024);          // 1

    const int Cin[4]  = {3, 96, 192, 384};
    const int Co[4]   = {96, 192, 384, 768};
    const int ooff[4] = {0, 96, 288, 672};
    const int soff[5] = {0, 96, 288, 672, 1440};
    const int woff[4] = {0, WOFF_L1, WOFF_L2, WOFF_L3};   // weight plane offsets (layers 1..3 used)

    hipLaunchKernelGGL(k_init, dim3(425), dim3(256), 0, stream, x, flag, xf, slots);
    hipLaunchKernelGGL(k_knn, dim3(NPTS), dim3(256), 0, stream, xf, idx);
    hipLaunchKernelGGL(k_wt_all, dim3((WTOTAL + 255) / 256), dim3(256), 0, stream,
                       d_in[4], d_in[7], d_in[10], d_in[13], flag, Whall, Wlall);

    const float invcnt_edge = 1.f / (float)(NPTS * KNB);
    for (int L = 0; L < 4; L++) {
        const void* g  = d_in[2 + 3 * L];
        const void* bb = d_in[3 + 3 * L];
        int N2 = 2 * Co[L];
        if (L == 0) {
            hipLaunchKernelGGL(k_l0, dim3((NPTS * 192 + 255) / 256), dim3(256), 0, stream,
                               xf, d_in[1], flag, Ub, Vf);
        } else {
            hipLaunchKernelGGL(k_gemm_mfma, dim3(N2 / 128, NPTS / 128, 1), dim3(256), 0, stream,
                               fch, fcl, FCATC, ooff[L - 1], Whall + woff[L], Wlall + woff[L], Cin[L],
                               Ub, Vf, Co[L], 0, Cin[L], 0);
        }
        int nchunks = ((Co[L] / 2) + 255) / 256;
        hipLaunchKernelGGL(k_gather, dim3(NPTS / PBATCH, nchunks), dim3(256), 0, stream,
                           Ub, Vf, idx, fch, fcl, ssum + soff[L], ssq + soff[L], Co[L], ooff[L]);
        hipLaunchKernelGGL(k_scaleshift, dim3((Co[L] + 255) / 256), dim3(256), 0, stream,
                           ssum + soff[L], ssq + soff[L], g, bb, flag,
                           scales + soff[L], shifts + soff[L], Co[L], invcnt_edge);
        hipLaunchKernelGGL(k_apply, dim3(NPTS), dim3(256), 0, stream,
                           Vf, scales + soff[L], shifts + soff[L], fch, fcl, Co[L], ooff[L]);
    }

    // final 1440 -> 256: split-K x5 into disjoint planes (reusing Ub/Vf region), then fused reduce+stats
    hipLaunchKernelGGL(k_gemm_mfma, dim3(256 / 128, NPTS / 128, 5), dim3(256), 0, stream,
                       fch, fcl, FCATC, 0, Whall + WOFF_F, Wlall + WOFF_F, FCATC,
                       (bf16*)nullptr, part, 0, 256, 288, NPTS * 256);
    hipLaunchKernelGGL(k_stats_final, dim3(32), dim3(256), 0, stream, part, Y4, ssum + soff[4], ssq + soff[4]);
    hipLaunchKernelGGL(k_feats, dim3(64), dim3(256), 0, stream, Y4, ssum + soff[4], ssq + soff[4],
                       d_in[14], d_in[15], flag, d_out, partial);
    hipLaunchKernelGGL(k_gmax, dim3(BATCH), dim3(256), 0, stream, partial, d_out, flag);
}

// Round 17
// 342.320 us; speedup vs baseline: 1.0401x; 1.0297x over previous
//
#include <hip/hip_runtime.h>
#include <hip/hip_bf16.h>

#define BATCH 2
#define NPB   2048
#define NPTS  4096   // BATCH*NPB
#define KNB   27
#define FCATC 1440
#define CSTRIDE 1696   // channel stride for slot partial sums (1440 + 256)
#define NSLOT 32
#define PBATCH 4       // points per gather block (atomic-traffic reduction)

// weight-plane segment offsets (elements): layer1 2*192x96, layer2 2*384x192, layer3 2*768x384, final 256x1440
#define WOFF_L1 0
#define WOFF_L2 36864
#define WOFF_L3 184320
#define WOFF_F  774144
#define WTOTAL  1142784

typedef __hip_bfloat16 bf16;
typedef __attribute__((ext_vector_type(8))) short short8;   // 8 bf16 = 4 VGPRs (MFMA A/B frag)
typedef __attribute__((ext_vector_type(4))) float f32x4;    // MFMA C/D frag
typedef __attribute__((ext_vector_type(2))) short s16x2;    // 2 bf16 = 4B vector

__device__ __forceinline__ float b2f(bf16 v) { return __bfloat162float(v); }

// split fp32 into hi/lo bf16 pair (hi + lo ~ 16 mantissa bits)
__device__ __forceinline__ void split_bf16(float v, bf16& h, bf16& l) {
    h = __float2bfloat16(v);
    l = __float2bfloat16(v - b2f(h));
}

// load input element i from buffer p whose dtype is fp32 (f32=1) or bf16 (f32=0)
__device__ __forceinline__ float ldin(const void* p, size_t i, int f32) {
    return f32 ? ((const float*)p)[i] : b2f(((const bf16*)p)[i]);
}

// ---------------- init: zero slot accumulators + dtype-detect + convert x (fused) ----------------
__global__ void k_init(const void* __restrict__ x, int* __restrict__ flag,
                       float* __restrict__ xf, float* __restrict__ slots) {
    if (blockIdx.x < 424) {
        slots[blockIdx.x * 256 + threadIdx.x] = 0.f;
        return;
    }
    __shared__ int s;
    if (threadIdx.x == 0) s = 0;
    __syncthreads();
    const bf16* xb = (const bf16*)x;
    int local = 0;
    for (int i = threadIdx.x; i < NPTS * 3; i += 256) {
        float v = b2f(xb[i]);
        if (!(fabsf(v) < 1e4f)) local = 1;   // catches NaN/Inf/huge -> underlying fp32
    }
    if (local) s = 1;
    __syncthreads();
    int f32 = s;
    if (threadIdx.x == 0) flag[0] = f32;
    for (int i = threadIdx.x; i < NPTS * 3; i += 256) xf[i] = ldin(x, i, f32);
}

// ---------------- KNN via 2-pass radix-select (16-bit prefix) + tie resolution ----------------
// Top-27 by max of negative sq dist. Keys order-preserving uint. 2 passes of 8 bits pick the
// 16-bit prefix bin containing the 27th-largest key; bin occupancy is ~1 for spread float keys,
// so the common case is tiecnt==rem (order-free write). Rare path: serial top-rem by
// (key desc, index asc) — identical set semantics to lax.top_k (lowest index on equal keys).
__global__ __launch_bounds__(256) void k_knn(const float* __restrict__ x, int* __restrict__ idx) {
    __shared__ uint hist4[4][260];   // per-wave copies, padded
    __shared__ uint hist[256];
    __shared__ uint tkey[NPB];
    __shared__ int  tix[NPB];
    __shared__ uint s_phigh;
    __shared__ int  s_rem, s_outcnt, s_tiecnt;

    int bn = blockIdx.x, b = bn >> 11, n = bn & (NPB - 1);
    int tid = threadIdx.x;
    int wv = tid >> 6;
    const float* xb = x + (size_t)b * NPB * 3;
    float cx = xb[n * 3 + 0], cy = xb[n * 3 + 1], cz = xb[n * 3 + 2];
    float cc = cx * cx + cy * cy + cz * cz;

    uint u[8];
    #pragma unroll
    for (int j = 0; j < 8; j++) {
        int m = j * 256 + tid;
        float mx = xb[m * 3 + 0], my = xb[m * 3 + 1], mz = xb[m * 3 + 2];
        float d = 2.f * (cx * mx + cy * my + cz * mz) - cc - (mx * mx + my * my + mz * mz);
        uint s = __float_as_uint(d);
        u[j] = (s & 0x80000000u) ? ~s : (s | 0x80000000u);
    }
    if (tid == 0) { s_phigh = 0; s_rem = KNB; s_outcnt = 0; s_tiecnt = 0; }

    for (int pass = 0; pass < 2; pass++) {
        int shift = 24 - pass * 8;
        hist[tid] = 0;
        for (int i = tid; i < 4 * 260; i += 256) ((uint*)hist4)[i] = 0;
        __syncthreads();
        uint phigh = s_phigh;
        #pragma unroll
        for (int j = 0; j < 8; j++) {
            bool in = (pass == 0) || ((u[j] >> (shift + 8)) == phigh);
            if (in) atomicAdd(&hist4[wv][(u[j] >> shift) & 0xFFu], 1u);
        }
        __syncthreads();
        hist[tid] = hist4[0][tid] + hist4[1][tid] + hist4[2][tid] + hist4[3][tid];
        __syncthreads();
        if (tid < 64) {
            int L = tid;
            uint c0 = hist[L * 4 + 0], c1 = hist[L * 4 + 1], c2 = hist[L * 4 + 2], c3 = hist[L * 4 + 3];
            uint s = c0 + c1 + c2 + c3;
            uint acc = s;
            #pragma unroll
            for (int off = 1; off < 64; off <<= 1) {
                uint t = __shfl_down(acc, off);
                if (L + off < 64) acc += t;
            }
            uint excl = acc - s;
            int rem = s_rem;
            if ((int)excl < rem && (int)acc >= rem) {
                uint cs[4] = { c0, c1, c2, c3 };
                uint cum = excl;
                int bsel = 0; uint hb = 0;
                #pragma unroll
                for (int q = 3; q >= 0; q--) {
                    if ((int)cum < rem && (int)(cum + cs[q]) >= rem && hb == 0u && bsel == 0) {
                        bsel = L * 4 + q; hb = cs[q]; cum += cs[q];
                    } else if (bsel == 0 && hb == 0u) {
                        cum += cs[q];
                    }
                }
                int strictlyAbove = (int)(cum - hb);
                s_rem = rem - strictlyAbove;
                s_phigh = (phigh << 8) | (uint)bsel;
            }
        }
        __syncthreads();
    }

    uint T16 = s_phigh;   // 16-bit prefix of the 27th-largest key
    #pragma unroll
    for (int j = 0; j < 8; j++) {
        int m = j * 256 + tid;
        uint hi = u[j] >> 16;
        if (hi > T16) {
            int p = atomicAdd(&s_outcnt, 1);
            idx[bn * KNB + p] = b * NPB + m;
        } else if (hi == T16) {
            int p = atomicAdd(&s_tiecnt, 1);
            tkey[p] = u[j];
            tix[p] = m;
        }
    }
    __syncthreads();
    int outcnt = s_outcnt, rem = s_rem, tiecnt = s_tiecnt;
    if (tiecnt == rem) {
        if (tid < rem) idx[bn * KNB + outcnt + tid] = b * NPB + tix[tid];
    } else if (tid == 0) {
        for (int t = 0; t < rem; t++) {
            int bi = 0;
            for (int q = 1; q < tiecnt; q++)
                if (tkey[q] > tkey[bi] || (tkey[q] == tkey[bi] && tix[q] < tix[bi])) bi = q;
            idx[bn * KNB + outcnt + t] = b * NPB + tix[bi];
            tkey[bi] = 0; tix[bi] = 0x7fffffff;
        }
    }
}

// ---------------- layer0 direct: u -> Ub bf16, v -> Vf f32 (Co=96) ----------------
__global__ void k_l0(const float* __restrict__ xf, const void* __restrict__ W,
                     const int* __restrict__ flag, bf16* __restrict__ Ub, float* __restrict__ Vf) {
    int i = blockIdx.x * 256 + threadIdx.x;
    if (i >= NPTS * 192) return;
    int bn = i / 192, o = i % 192;
    int f32 = flag[0];
    float x0 = xf[bn * 3 + 0], x1 = xf[bn * 3 + 1], x2 = xf[bn * 3 + 2];
    if (o < 96) {
        float r = x0 * ldin(W, o * 6 + 0, f32) + x1 * ldin(W, o * 6 + 1, f32) + x2 * ldin(W, o * 6 + 2, f32);
        Ub[(size_t)bn * 96 + o] = __float2bfloat16(r);
    } else {
        int oo = o - 96;
        float w0 = ldin(W, oo * 6 + 3, f32) - ldin(W, oo * 6 + 0, f32);
        float w1 = ldin(W, oo * 6 + 4, f32) - ldin(W, oo * 6 + 1, f32);
        float w2 = ldin(W, oo * 6 + 5, f32) - ldin(W, oo * 6 + 2, f32);
        Vf[(size_t)bn * 96 + oo] = x0 * w0 + x1 * w1 + x2 * w2;
    }
}

// ---------------- ALL weight transforms in one kernel -> contiguous hi/lo planes ----------------
__global__ void k_wt_all(const void* __restrict__ W1, const void* __restrict__ W2,
                         const void* __restrict__ W3, const void* __restrict__ W4,
                         const int* __restrict__ flag,
                         bf16* __restrict__ Wh, bf16* __restrict__ Wl) {
    int i = blockIdx.x * 256 + threadIdx.x;
    if (i >= WTOTAL) return;
    int f32 = flag[0];
    float w;
    if (i < WOFF_L2) {                     // layer1: Cin=96, Co=192, 2Cin=192
        int row = i / 96, c = i % 96;
        w = (row < 192) ? ldin(W1, (size_t)row * 192 + c, f32)
                        : ldin(W1, (size_t)(row - 192) * 192 + 96 + c, f32)
                          - ldin(W1, (size_t)(row - 192) * 192 + c, f32);
    } else if (i < WOFF_L3) {              // layer2: Cin=192, Co=384, 2Cin=384
        int j = i - WOFF_L2;
        int row = j / 192, c = j % 192;
        w = (row < 384) ? ldin(W2, (size_t)row * 384 + c, f32)
                        : ldin(W2, (size_t)(row - 384) * 384 + 192 + c, f32)
                          - ldin(W2, (size_t)(row - 384) * 384 + c, f32);
    } else if (i < WOFF_F) {               // layer3: Cin=384, Co=768, 2Cin=768
        int j = i - WOFF_L3;
        int row = j / 384, c = j % 384;
        w = (row < 768) ? ldin(W3, (size_t)row * 768 + c, f32)
                        : ldin(W3, (size_t)(row - 768) * 768 + 384 + c, f32)
                          - ldin(W3, (size_t)(row - 768) * 768 + c, f32);
    } else {                               // final: 256 x 1440 direct
        int j = i - WOFF_F;
        w = ldin(W4, j, f32);
    }
    bf16 h, l; split_bf16(w, h, l);
    Wh[i] = h; Wl[i] = l;
}

// ---------------- split-precision MFMA GEMM: C = (Ah+Al) * (Bh+Bl)^T, ~fp32 accuracy ----------------
// 64x64 block (round-14 config, measured best). XCD m-stripe swizzle (gridDim.y == 64).
// Cosplit>0: cols [0,Cosplit)->Cu bf16, rest->Cv f32; Cosplit==0: f32 split-K plane write.
__global__ __launch_bounds__(256) void k_gemm_mfma(const bf16* __restrict__ Ah, const bf16* __restrict__ Al,
                                                   int lda, int aoff,
                                                   const bf16* __restrict__ Bh, const bf16* __restrict__ Bl,
                                                   int K, bf16* __restrict__ Cu, float* __restrict__ Cv,
                                                   int Cosplit, int ldc, int ksz, int zstride) {
    __shared__ bf16 Ash[64][40];   // +8 pad: 2-way max bank aliasing
    __shared__ bf16 Asl[64][40];
    __shared__ bf16 Bsh[64][40];
    __shared__ bf16 Bsl[64][40];
    int tid = threadIdx.x;
    int wave = tid >> 6, lane = tid & 63;
    int wm = wave >> 1, wn = wave & 1;
    int quad = lane >> 4, l15 = lane & 15;
    int Lxy = blockIdx.y * gridDim.x + blockIdx.x;
    int stripe = Lxy & 7;
    int w = Lxy >> 3;
    int mb = stripe * 8 + (w & 7);
    int nb = w >> 3;
    int m0 = mb * 64, n0 = nb * 64;
    int kbase = blockIdx.z * ksz;
    float* Cz = Cv + (size_t)blockIdx.z * zstride;
    int lr = tid >> 2, lc = (tid & 3) * 8;

    f32x4 acc[2][2] = {};
    for (int k0 = kbase; k0 < kbase + ksz; k0 += 32) {
        size_t ao = (size_t)(m0 + lr) * lda + aoff + k0 + lc;
        size_t bo = (size_t)(n0 + lr) * K + k0 + lc;
        *(short8*)&Ash[lr][lc] = *(const short8*)&Ah[ao];
        *(short8*)&Asl[lr][lc] = *(const short8*)&Al[ao];
        *(short8*)&Bsh[lr][lc] = *(const short8*)&Bh[bo];
        *(short8*)&Bsl[lr][lc] = *(const short8*)&Bl[bo];
        __syncthreads();
        short8 ah0 = *(const short8*)&Ash[wm * 32 + l15][quad * 8];
        short8 ah1 = *(const short8*)&Ash[wm * 32 + 16 + l15][quad * 8];
        short8 al0 = *(const short8*)&Asl[wm * 32 + l15][quad * 8];
        short8 al1 = *(const short8*)&Asl[wm * 32 + 16 + l15][quad * 8];
        short8 bh0 = *(const short8*)&Bsh[wn * 32 + l15][quad * 8];
        short8 bh1 = *(const short8*)&Bsh[wn * 32 + 16 + l15][quad * 8];
        short8 bl0 = *(const short8*)&Bsl[wn * 32 + l15][quad * 8];
        short8 bl1 = *(const short8*)&Bsl[wn * 32 + 16 + l15][quad * 8];
        acc[0][0] = __builtin_amdgcn_mfma_f32_16x16x32_bf16(ah0, bl0, acc[0][0], 0, 0, 0);
        acc[0][0] = __builtin_amdgcn_mfma_f32_16x16x32_bf16(al0, bh0, acc[0][0], 0, 0, 0);
        acc[0][0] = __builtin_amdgcn_mfma_f32_16x16x32_bf16(ah0, bh0, acc[0][0], 0, 0, 0);
        acc[0][1] = __builtin_amdgcn_mfma_f32_16x16x32_bf16(ah0, bl1, acc[0][1], 0, 0, 0);
        acc[0][1] = __builtin_amdgcn_mfma_f32_16x16x32_bf16(al0, bh1, acc[0][1], 0, 0, 0);
        acc[0][1] = __builtin_amdgcn_mfma_f32_16x16x32_bf16(ah0, bh1, acc[0][1], 0, 0, 0);
        acc[1][0] = __builtin_amdgcn_mfma_f32_16x16x32_bf16(ah1, bl0, acc[1][0], 0, 0, 0);
        acc[1][0] = __builtin_amdgcn_mfma_f32_16x16x32_bf16(al1, bh0, acc[1][0], 0, 0, 0);
        acc[1][0] = __builtin_amdgcn_mfma_f32_16x16x32_bf16(ah1, bh0, acc[1][0], 0, 0, 0);
        acc[1][1] = __builtin_amdgcn_mfma_f32_16x16x32_bf16(ah1, bl1, acc[1][1], 0, 0, 0);
        acc[1][1] = __builtin_amdgcn_mfma_f32_16x16x32_bf16(al1, bh1, acc[1][1], 0, 0, 0);
        acc[1][1] = __builtin_amdgcn_mfma_f32_16x16x32_bf16(ah1, bh1, acc[1][1], 0, 0, 0);
        __syncthreads();
    }
    #pragma unroll
    for (int mt = 0; mt < 2; mt++) {
        #pragma unroll
        for (int nt = 0; nt < 2; nt++) {
            int col = n0 + wn * 32 + nt * 16 + l15;
            #pragma unroll
            for (int i = 0; i < 4; i++) {
                int row = m0 + wm * 32 + mt * 16 + quad * 4 + i;
                if (Cosplit > 0) {
                    if (col < Cosplit) Cu[(size_t)row * Cosplit + col] = __float2bfloat16(acc[mt][nt][i]);
                    else               Cv[(size_t)row * Cosplit + col - Cosplit] = acc[mt][nt][i];
                } else {
                    Cz[(size_t)row * ldc + col] = acc[mt][nt][i];
                }
            }
        }
    }
}

// ---------------- fused gather: 2 channels/thread (uint = 2x bf16), XCD-aware swizzle ----------------
__global__ __launch_bounds__(256) void k_gather(const bf16* __restrict__ Ub, float* __restrict__ Vf,
                                                const int* __restrict__ idx,
                                                bf16* __restrict__ fch, bf16* __restrict__ fcl,
                                                float* __restrict__ ssum, float* __restrict__ ssq,
                                                int Co, int out_off) {
    __shared__ int srow[PBATCH * KNB];
    int tid = threadIdx.x;
    int L = blockIdx.y * gridDim.x + blockIdx.x;
    int batch = L & 1;
    int w = L >> 1;
    int pg = batch * 512 + (w & 511);       // point group within [0,1024)
    int chunk = w >> 9;                     // channel-pair chunk
    int p0 = pg * PBATCH;
    if (tid < PBATCH * KNB) srow[tid] = idx[p0 * KNB + tid] * Co;
    __syncthreads();
    int P = Co >> 1;
    int op = chunk * 256 + tid;
    if (op >= P) return;
    int o = op * 2;
    int slot = pg & (NSLOT - 1);
    float s0 = 0.f, s1 = 0.f, q0 = 0.f, q1 = 0.f;
    #pragma unroll 1
    for (int p = 0; p < PBATCH; p++) {
        int bn = p0 + p;
        float2 vv = *(const float2*)&Vf[(size_t)bn * Co + o];
        float ymax0 = -INFINITY, ymax1 = -INFINITY, ymin0 = INFINITY, ymin1 = INFINITY;
        #pragma unroll
        for (int k = 0; k < KNB; k++) {
            uint wb = *(const uint*)&Ub[(size_t)srow[p * KNB + k] + o];
            float y0 = __uint_as_float(wb << 16) + vv.x;
            float y1 = __uint_as_float(wb & 0xffff0000u) + vv.y;
            ymax0 = fmaxf(ymax0, y0); ymin0 = fminf(ymin0, y0); s0 += y0; q0 += y0 * y0;
            ymax1 = fmaxf(ymax1, y1); ymin1 = fminf(ymin1, y1); s1 += y1; q1 += y1 * y1;
        }
        size_t fi = (size_t)bn * FCATC + out_off + o;
        bf16 hh[2], ll[2];
        split_bf16(ymax0, hh[0], ll[0]);
        split_bf16(ymax1, hh[1], ll[1]);
        *(s16x2*)&fch[fi] = *(const s16x2*)hh;
        *(s16x2*)&fcl[fi] = *(const s16x2*)ll;
        *(float2*)&Vf[(size_t)bn * Co + o] = make_float2(ymin0, ymin1);   // stash ymin
    }
    atomicAdd(&ssum[slot * CSTRIDE + o + 0], s0);
    atomicAdd(&ssum[slot * CSTRIDE + o + 1], s1);
    atomicAdd(&ssq [slot * CSTRIDE + o + 0], q0);
    atomicAdd(&ssq [slot * CSTRIDE + o + 1], q1);
}

// ---------------- scale/shift from 32-slot partials (edge layers) ----------------
__global__ void k_scaleshift(const float* __restrict__ ssum, const float* __restrict__ ssq,
                             const void* __restrict__ g, const void* __restrict__ bb,
                             const int* __restrict__ flag,
                             float* __restrict__ scale, float* __restrict__ shift, int Co, float invcnt) {
    int o = blockIdx.x * 256 + threadIdx.x;
    if (o >= Co) return;
    int f32 = flag[0];
    float s = 0.f, q = 0.f;
    for (int c = 0; c < NSLOT; c++) { s += ssum[c * CSTRIDE + o]; q += ssq[c * CSTRIDE + o]; }
    float mean = s * invcnt;
    float var = q * invcnt - mean * mean;
    float sc = ldin(g, o, f32) * rsqrtf(var + 1e-5f);
    scale[o] = sc;
    shift[o] = ldin(bb, o, f32) - mean * sc;
}

// ---------------- apply BN + lrelu to the pooled value (in place in fcat hi/lo) ----------------
__global__ __launch_bounds__(256) void k_apply(const float* __restrict__ Vf,
                                               const float* __restrict__ scale, const float* __restrict__ shift,
                                               bf16* __restrict__ fch, bf16* __restrict__ fcl,
                                               int Co, int out_off) {
    int bn = blockIdx.x;
    for (int o = threadIdx.x; o < Co; o += 256) {
        float sc = scale[o], sh = shift[o];
        size_t fi = (size_t)bn * FCATC + out_off + o;
        float y = (sc >= 0.f) ? (b2f(fch[fi]) + b2f(fcl[fi]))
                              : Vf[(size_t)bn * Co + o];           // ymin if negative scale
        float z = sc * y + sh;
        z = (z >= 0.f) ? z : 0.2f * z;
        bf16 h, l; split_bf16(z, h, l);
        fch[fi] = h; fcl[fi] = l;
    }
}

// ---------------- final: reduce 5 split-K planes -> Y4 + BN stats (no atomics) ----------------
__global__ void k_stats_final(const float* __restrict__ part, float* __restrict__ Y,
                              float* __restrict__ ssum, float* __restrict__ ssq) {
    int o = threadIdx.x;
    int p0 = blockIdx.x * 128;
    const size_t PL = (size_t)NPTS * 256;
    float s = 0, q = 0;
    for (int p = 0; p < 128; p++) {
        size_t i = (size_t)(p0 + p) * 256 + o;
        float y = part[i] + part[i + PL] + part[i + 2 * PL] + part[i + 3 * PL] + part[i + 4 * PL];
        Y[i] = y;
        s += y; q += y * y;
    }
    ssum[blockIdx.x * CSTRIDE + o] = s;
    ssq [blockIdx.x * CSTRIDE + o] = q;
}

// ---------------- feats: fused final scale/shift + BN + lrelu + per-chunk max ----------------
__global__ void k_feats(const float* __restrict__ Y, const float* __restrict__ ssum,
                        const float* __restrict__ ssq, const void* __restrict__ g,
                        const void* __restrict__ bb, const int* __restrict__ flag,
                        void* __restrict__ out, float* __restrict__ partial) {
    int o = threadIdx.x;
    int chunk = blockIdx.x;
    int bn0 = chunk * 64;
    int f32 = flag[0];
    float s = 0.f, q = 0.f;
    for (int c = 0; c < NSLOT; c++) { s += ssum[c * CSTRIDE + o]; q += ssq[c * CSTRIDE + o]; }
    float mean = s * (1.f / (float)NPTS);
    float var = q * (1.f / (float)NPTS) - mean * mean;
    float sc = ldin(g, o, f32) * rsqrtf(var + 1e-5f);
    float sh = ldin(bb, o, f32) - mean * sc;
    float best = -INFINITY;
    for (int i = 0; i < 64; i++) {
        int bn = bn0 + i;
        float z = sc * Y[(size_t)bn * 256 + o] + sh;
        z = (z >= 0.f) ? z : 0.2f * z;
        size_t oi = (size_t)BATCH * 256 + (size_t)bn * 256 + o;
        if (f32) ((float*)out)[oi] = z;
        else     ((bf16*)out)[oi] = __float2bfloat16(z);
        best = fmaxf(best, z);
    }
    partial[chunk * 256 + o] = best;
}

__global__ void k_gmax(const float* __restrict__ partial, void* __restrict__ out, const int* __restrict__ flag) {
    int o = threadIdx.x;
    int b = blockIdx.x;
    float best = -INFINITY;
    for (int c = 0; c < 32; c++) best = fmaxf(best, partial[(b * 32 + c) * 256 + o]);
    if (flag[0]) ((float*)out)[b * 256 + o] = best;
    else         ((bf16*)out)[b * 256 + o] = __float2bfloat16(best);
}

// ---------------- launch ----------------
extern "C" void kernel_launch(void* const* d_in, const int* in_sizes, int n_in,
                              void* d_out, int out_size, void* d_ws, size_t ws_size,
                              hipStream_t stream) {
    const void* x = d_in[0];

    char* ws = (char*)d_ws;
    int*   idx    = (int*)  (ws + 0);                 // 4096*27 int
    bf16*  Ub     = (bf16*) (ws + 442368);            // 4096 x 768 bf16 (u, 6.29 MB)
    float* Vf     = (float*)(ws + 6733824);           // 4096 x 768 f32 (v/ymin, 12.58 MB)
    float* part   = (float*)(ws + 442368);            // reused after layers: 5 x 4096 x 256 f32 (21 MB)
    bf16*  fch    = (bf16*) (ws + 25608192);          // 4096 x 1440 bf16 (hi)
    bf16*  fcl    = (bf16*) (ws + 37404672);          // 4096 x 1440 bf16 (lo)
    float* Y4     = (float*)(ws + 49201152);          // 4096 x 256 f32
    bf16*  Whall  = (bf16*) (ws + 53395456);          // WTOTAL bf16 (hi planes, 2.29 MB)
    bf16*  Wlall  = (bf16*) (ws + 55681024);          // WTOTAL bf16 (lo planes)
    float* slots  = (float*)(ws + 57966592);          // 2 x 32 x 1696 f32 (434176 B)
    float* ssum   = slots;
    float* ssq    = slots + NSLOT * CSTRIDE;
    float* scales = (float*)(ws + 58400768);          // 1696
    float* shifts = (float*)(ws + 58407552);          // 1696
    float* partial= (float*)(ws + 58414336);          // 64 x 256
    float* xf     = (float*)(ws + 58479872);          // 12288 f32
    int*   flag   = (int*)  (ws + 58529024);          // 1

    const int Cin[4]  = {3, 96, 192, 384};
    const int Co[4]   = {96, 192, 384, 768};
    const int ooff[4] = {0, 96, 288, 672};
    const int soff[5] = {0, 96, 288, 672, 1440};
    const int woff[4] = {0, WOFF_L1, WOFF_L2, WOFF_L3};   // weight plane offsets (layers 1..3 used)

    hipLaunchKernelGGL(k_init, dim3(425), dim3(256), 0, stream, x, flag, xf, slots);
    hipLaunchKernelGGL(k_knn, dim3(NPTS), dim3(256), 0, stream, xf, idx);
    hipLaunchKernelGGL(k_wt_all, dim3((WTOTAL + 255) / 256), dim3(256), 0, stream,
                       d_in[4], d_in[7], d_in[10], d_in[13], flag, Whall, Wlall);

    const float invcnt_edge = 1.f / (float)(NPTS * KNB);
    for (int L = 0; L < 4; L++) {
        const void* g  = d_in[2 + 3 * L];
        const void* bb = d_in[3 + 3 * L];
        int N2 = 2 * Co[L];
        if (L == 0) {
            hipLaunchKernelGGL(k_l0, dim3((NPTS * 192 + 255) / 256), dim3(256), 0, stream,
                               xf, d_in[1], flag, Ub, Vf);
        } else {
            hipLaunchKernelGGL(k_gemm_mfma, dim3(N2 / 64, NPTS / 64, 1), dim3(256), 0, stream,
                               fch, fcl, FCATC, ooff[L - 1], Whall + woff[L], Wlall + woff[L], Cin[L],
                               Ub, Vf, Co[L], 0, Cin[L], 0);
        }
        int nchunks = ((Co[L] / 2) + 255) / 256;
        hipLaunchKernelGGL(k_gather, dim3(NPTS / PBATCH, nchunks), dim3(256), 0, stream,
                           Ub, Vf, idx, fch, fcl, ssum + soff[L], ssq + soff[L], Co[L], ooff[L]);
        hipLaunchKernelGGL(k_scaleshift, dim3((Co[L] + 255) / 256), dim3(256), 0, stream,
                           ssum + soff[L], ssq + soff[L], g, bb, flag,
                           scales + soff[L], shifts + soff[L], Co[L], invcnt_edge);
        hipLaunchKernelGGL(k_apply, dim3(NPTS), dim3(256), 0, stream,
                           Vf, scales + soff[L], shifts + soff[L], fch, fcl, Co[L], ooff[L]);
    }

    // final 1440 -> 256: split-K x5 into disjoint planes (reusing Ub/Vf region), then fused reduce+stats
    hipLaunchKernelGGL(k_gemm_mfma, dim3(256 / 64, NPTS / 64, 5), dim3(256), 0, stream,
                       fch, fcl, FCATC, 0, Whall + WOFF_F, Wlall + WOFF_F, FCATC,
                       (bf16*)nullptr, part, 0, 256, 288, NPTS * 256);
    hipLaunchKernelGGL(k_stats_final, dim3(32), dim3(256), 0, stream, part, Y4, ssum + soff[4], ssq + soff[4]);
    hipLaunchKernelGGL(k_feats, dim3(64), dim3(256), 0, stream, Y4, ssum + soff[4], ssq + soff[4],
                       d_in[14], d_in[15], flag, d_out, partial);
    hipLaunchKernelGGL(k_gmax, dim3(BATCH), dim3(256), 0, stream, partial, d_out, flag);
}